// Round 1
// baseline (308.292 us; speedup 1.0000x reference)
//
#include <hip/hip_runtime.h>
#include <hip/hip_bf16.h>

#define NN 10000
#define EE 320000
#define ET (EE + NN)   // edges + self loops
#define FIN 256

// ---------------- CSR build ----------------

__global__ void k_zero(int* deg) {
    int i = blockIdx.x * blockDim.x + threadIdx.x;
    if (i < NN) deg[i] = 0;
}

__global__ void k_count(const int* __restrict__ ei, int* __restrict__ deg) {
    int e = blockIdx.x * blockDim.x + threadIdx.x;
    if (e >= ET) return;
    int d = (e < EE) ? ei[EE + e] : (e - EE);
    atomicAdd(&deg[d], 1);
}

__global__ void k_scan(const int* __restrict__ deg, int* __restrict__ rowptr,
                       int* __restrict__ cursor) {
    __shared__ int sums[1024];
    int tid = threadIdx.x;
    const int per = (NN + 1023) >> 10;          // 10
    int start = tid * per;
    int end   = start + per; if (end > NN) end = NN;
    int local = 0;
    if (start < NN)
        for (int i = start; i < end; i++) local += deg[i];
    sums[tid] = local;
    __syncthreads();
    for (int off = 1; off < 1024; off <<= 1) {
        int v = (tid >= off) ? sums[tid - off] : 0;
        __syncthreads();
        sums[tid] += v;
        __syncthreads();
    }
    int run = sums[tid] - local;                // exclusive prefix
    if (start < NN)
        for (int i = start; i < end; i++) { rowptr[i] = run; cursor[i] = run; run += deg[i]; }
    if (tid == 1023) rowptr[NN] = run;          // total = ET
}

__global__ void k_scatter(const int* __restrict__ ei, int* __restrict__ cursor,
                          int* __restrict__ csr_src) {
    int e = blockIdx.x * blockDim.x + threadIdx.x;
    if (e >= ET) return;
    int s, d;
    if (e < EE) { s = ei[e]; d = ei[EE + e]; }
    else        { s = e - EE; d = s; }
    int pos = atomicAdd(&cursor[d], 1);
    csr_src[pos] = s;
}

// ---------------- layer 1 ----------------

// xl1[n,64] = x[n,256] @ W1[256,64]
__global__ void k_gemm1(const float* __restrict__ x, const float* __restrict__ W1,
                        float* __restrict__ xl1) {
    int idx = blockIdx.x * blockDim.x + threadIdx.x;
    if (idx >= NN * 64) return;
    int n = idx >> 6, col = idx & 63;
    const float* xr = x + n * FIN;
    float acc = 0.f;
#pragma unroll 8
    for (int k = 0; k < FIN; k++) acc += xr[k] * W1[k * 64 + col];
    xl1[idx] = acc;
}

// a_src1[n,8], a_dst1[n,8]
__global__ void k_att1(const float* __restrict__ xl1, const float* __restrict__ as,
                       const float* __restrict__ ad, float* __restrict__ a_src,
                       float* __restrict__ a_dst) {
    int n = blockIdx.x, l = threadIdx.x;
    float v = xl1[n * 64 + l];
    float ps = v * as[l], pd = v * ad[l];
    for (int off = 4; off; off >>= 1) {
        ps += __shfl_xor(ps, off);
        pd += __shfl_xor(pd, off);
    }
    if ((l & 7) == 0) {
        a_src[n * 8 + (l >> 3)] = ps;
        a_dst[n * 8 + (l >> 3)] = pd;
    }
}

// per-dst softmax + aggregate + bias + ELU -> h[n,64]
__global__ void k_gat1(const int* __restrict__ rowptr, const int* __restrict__ csr_src,
                       const float* __restrict__ xl1, const float* __restrict__ a_src,
                       const float* __restrict__ a_dst, const float* __restrict__ b1,
                       float* __restrict__ hout) {
    int d = blockIdx.x, l = threadIdx.x;
    int h = l >> 3;
    float adst = a_dst[d * 8 + h];
    int rs = rowptr[d], re = rowptr[d + 1];
    float m = -1e30f;
    for (int i = rs; i < re; i++) {
        float e = a_src[csr_src[i] * 8 + h] + adst;
        e = (e > 0.f) ? e : 0.2f * e;
        m = fmaxf(m, e);
    }
    float den = 0.f, acc = 0.f;
    for (int i = rs; i < re; i++) {
        int s = csr_src[i];
        float e = a_src[s * 8 + h] + adst;
        e = (e > 0.f) ? e : 0.2f * e;
        float w = expf(e - m);
        den += w;
        acc += w * xl1[s * 64 + l];
    }
    float o = acc / den + b1[l];
    o = (o > 0.f) ? o : (expf(o) - 1.f);       // ELU
    hout[d * 64 + l] = o;
}

// ---------------- layer 2 ----------------

// xl2[n,256] = h[n,64] @ W2[64,256]
__global__ void k_gemm2(const float* __restrict__ h, const float* __restrict__ W2,
                        float* __restrict__ xl2) {
    int idx = blockIdx.x * blockDim.x + threadIdx.x;
    if (idx >= NN * 256) return;
    int n = idx >> 8, c = idx & 255;
    const float* hr = h + n * 64;
    float acc = 0.f;
#pragma unroll 8
    for (int k = 0; k < 64; k++) acc += hr[k] * W2[k * 256 + c];
    xl2[idx] = acc;
}

__global__ void k_att2(const float* __restrict__ xl2, const float* __restrict__ as,
                       const float* __restrict__ ad, float* __restrict__ a_src,
                       float* __restrict__ a_dst) {
    int n = blockIdx.x, l = threadIdx.x;
    const float* xr = xl2 + n * 256;
    float ps = 0.f, pd = 0.f;
#pragma unroll
    for (int j = 0; j < 4; j++) {
        float v = xr[l + 64 * j];
        ps += v * as[l + 64 * j];
        pd += v * ad[l + 64 * j];
    }
    for (int off = 32; off; off >>= 1) {
        ps += __shfl_xor(ps, off);
        pd += __shfl_xor(pd, off);
    }
    if (l == 0) { a_src[n] = ps; a_dst[n] = pd; }
}

// per-dst softmax + aggregate + bias -> out[n,256]
__global__ void k_gat2(const int* __restrict__ rowptr, const int* __restrict__ csr_src,
                       const float* __restrict__ xl2, const float* __restrict__ a_src,
                       const float* __restrict__ a_dst, const float* __restrict__ b2,
                       float* __restrict__ out) {
    int d = blockIdx.x, l = threadIdx.x;
    float adst = a_dst[d];
    int rs = rowptr[d], re = rowptr[d + 1];
    float m = -1e30f;
    for (int i = rs; i < re; i++) {
        float e = a_src[csr_src[i]] + adst;
        e = (e > 0.f) ? e : 0.2f * e;
        m = fmaxf(m, e);
    }
    float den = 0.f, a0 = 0.f, a1 = 0.f, a2 = 0.f, a3 = 0.f;
    for (int i = rs; i < re; i++) {
        int s = csr_src[i];
        float e = a_src[s] + adst;
        e = (e > 0.f) ? e : 0.2f * e;
        float w = expf(e - m);
        den += w;
        const float* xr = xl2 + s * 256;
        a0 += w * xr[l];
        a1 += w * xr[l + 64];
        a2 += w * xr[l + 128];
        a3 += w * xr[l + 192];
    }
    float inv = 1.f / den;
    out[d * 256 + l]       = a0 * inv + b2[l];
    out[d * 256 + l + 64]  = a1 * inv + b2[l + 64];
    out[d * 256 + l + 128] = a2 * inv + b2[l + 128];
    out[d * 256 + l + 192] = a3 * inv + b2[l + 192];
}

// ---------------- launch ----------------

extern "C" void kernel_launch(void* const* d_in, const int* in_sizes, int n_in,
                              void* d_out, int out_size, void* d_ws, size_t ws_size,
                              hipStream_t stream) {
    const float* x   = (const float*)d_in[0];
    const int*   ei  = (const int*)d_in[1];
    const float* W1  = (const float*)d_in[2];
    const float* as1 = (const float*)d_in[3];
    const float* ad1 = (const float*)d_in[4];
    const float* b1  = (const float*)d_in[5];
    const float* W2  = (const float*)d_in[6];
    const float* as2 = (const float*)d_in[7];
    const float* ad2 = (const float*)d_in[8];
    const float* b2  = (const float*)d_in[9];
    float* out = (float*)d_out;

    char* p = (char*)d_ws;
    auto alloc = [&](size_t bytes) {
        void* r = (void*)p;
        p += (bytes + 255) & ~size_t(255);
        return r;
    };
    int*   deg     = (int*)alloc(NN * 4);
    int*   rowptr  = (int*)alloc((NN + 1) * 4);
    int*   cursor  = (int*)alloc(NN * 4);
    int*   csr_src = (int*)alloc((size_t)ET * 4);
    float* xl1     = (float*)alloc((size_t)NN * 64 * 4);
    float* asrc1   = (float*)alloc((size_t)NN * 8 * 4);
    float* adst1   = (float*)alloc((size_t)NN * 8 * 4);
    float* hbuf    = (float*)alloc((size_t)NN * 64 * 4);
    float* xl2     = (float*)alloc((size_t)NN * 256 * 4);
    float* asrc2   = (float*)alloc((size_t)NN * 4);
    float* adst2   = (float*)alloc((size_t)NN * 4);

    // CSR build
    k_zero<<<(NN + 255) / 256, 256, 0, stream>>>(deg);
    k_count<<<(ET + 255) / 256, 256, 0, stream>>>(ei, deg);
    k_scan<<<1, 1024, 0, stream>>>(deg, rowptr, cursor);
    k_scatter<<<(ET + 255) / 256, 256, 0, stream>>>(ei, cursor, csr_src);

    // layer 1
    k_gemm1<<<(NN * 64 + 255) / 256, 256, 0, stream>>>(x, W1, xl1);
    k_att1<<<NN, 64, 0, stream>>>(xl1, as1, ad1, asrc1, adst1);
    k_gat1<<<NN, 64, 0, stream>>>(rowptr, csr_src, xl1, asrc1, adst1, b1, hbuf);

    // layer 2
    k_gemm2<<<(NN * 256 + 255) / 256, 256, 0, stream>>>(hbuf, W2, xl2);
    k_att2<<<NN, 64, 0, stream>>>(xl2, as2, ad2, asrc2, adst2);
    k_gat2<<<NN, 64, 0, stream>>>(rowptr, csr_src, xl2, asrc2, adst2, b2, out);
}

// Round 2
// 233.423 us; speedup vs baseline: 1.3207x; 1.3207x over previous
//
#include <hip/hip_runtime.h>
#include <hip/hip_bf16.h>

#define NN 10000
#define EE 320000
#define ET (EE + NN)   // edges + self loops
#define FIN 256

// ---------------- CSR build ----------------

__global__ void k_zero(int* deg) {
    int i = blockIdx.x * blockDim.x + threadIdx.x;
    if (i < NN) deg[i] = 0;
}

__global__ void k_count(const int* __restrict__ ei, int* __restrict__ deg) {
    int e = blockIdx.x * blockDim.x + threadIdx.x;
    if (e >= ET) return;
    int d = (e < EE) ? ei[EE + e] : (e - EE);
    atomicAdd(&deg[d], 1);
}

__global__ void k_scan(const int* __restrict__ deg, int* __restrict__ rowptr,
                       int* __restrict__ cursor) {
    __shared__ int sums[1024];
    int tid = threadIdx.x;
    const int per = (NN + 1023) >> 10;          // 10
    int start = tid * per;
    int end   = start + per; if (end > NN) end = NN;
    int local = 0;
    if (start < NN)
        for (int i = start; i < end; i++) local += deg[i];
    sums[tid] = local;
    __syncthreads();
    for (int off = 1; off < 1024; off <<= 1) {
        int v = (tid >= off) ? sums[tid - off] : 0;
        __syncthreads();
        sums[tid] += v;
        __syncthreads();
    }
    int run = sums[tid] - local;                // exclusive prefix
    if (start < NN)
        for (int i = start; i < end; i++) { rowptr[i] = run; cursor[i] = run; run += deg[i]; }
    if (tid == 1023) rowptr[NN] = run;          // total = ET
}

__global__ void k_scatter(const int* __restrict__ ei, int* __restrict__ cursor,
                          int* __restrict__ csr_src) {
    int e = blockIdx.x * blockDim.x + threadIdx.x;
    if (e >= ET) return;
    int s, d;
    if (e < EE) { s = ei[e]; d = ei[EE + e]; }
    else        { s = e - EE; d = s; }
    int pos = atomicAdd(&cursor[d], 1);
    csr_src[pos] = s;
}

// ---------------- watt = W2 @ att2 (tiny) ----------------

__global__ void k_watt(const float* __restrict__ W2, const float* __restrict__ as2,
                       const float* __restrict__ ad2, float* __restrict__ wsrc,
                       float* __restrict__ wdst) {
    int t = threadIdx.x;          // 0..127
    int k = t & 63;
    const float* av = (t < 64) ? as2 : ad2;
    float acc = 0.f;
#pragma unroll
    for (int c4 = 0; c4 < 64; c4++) {
        float4 w = *(const float4*)&W2[k * 256 + c4 * 4];
        float4 a = *(const float4*)&av[c4 * 4];
        acc += w.x * a.x + w.y * a.y + w.z * a.z + w.w * a.w;
    }
    if (t < 64) wsrc[k] = acc; else wdst[k] = acc;
}

// ---------------- layer 1: GEMM + fused attention scores ----------------

// xl1[n,64] = x[n,256] @ W1[256,64];  a_src1[n,8], a_dst1[n,8] fused epilogue.
// 16 threads per node, 4 cols each. grid*block == NN*16 exactly.
__global__ __launch_bounds__(256) void k_gemm1(
        const float* __restrict__ x, const float* __restrict__ W1,
        const float* __restrict__ as1, const float* __restrict__ ad1,
        float* __restrict__ xl1, float* __restrict__ a_src1, float* __restrict__ a_dst1) {
    int tid = blockIdx.x * 256 + threadIdx.x;
    int n = tid >> 4, t = tid & 15;
    int c0 = t * 4;
    const float4* xr = (const float4*)(x + n * FIN);
    float acc0 = 0.f, acc1 = 0.f, acc2 = 0.f, acc3 = 0.f;
    for (int k4 = 0; k4 < 64; k4++) {
        float4 xv = xr[k4];
#pragma unroll
        for (int j = 0; j < 4; j++) {
            float xs = (j == 0) ? xv.x : (j == 1) ? xv.y : (j == 2) ? xv.z : xv.w;
            float4 w = *(const float4*)&W1[(k4 * 4 + j) * 64 + c0];
            acc0 += xs * w.x; acc1 += xs * w.y; acc2 += xs * w.z; acc3 += xs * w.w;
        }
    }
    *(float4*)&xl1[n * 64 + c0] = make_float4(acc0, acc1, acc2, acc3);
    // fused att1: head h = t>>1; att arrays are [8,8] flat = col index
    float ps = acc0 * as1[c0] + acc1 * as1[c0 + 1] + acc2 * as1[c0 + 2] + acc3 * as1[c0 + 3];
    float pd = acc0 * ad1[c0] + acc1 * ad1[c0 + 1] + acc2 * ad1[c0 + 2] + acc3 * ad1[c0 + 3];
    ps += __shfl_xor(ps, 1);
    pd += __shfl_xor(pd, 1);
    if ((t & 1) == 0) {
        a_src1[n * 8 + (t >> 1)] = ps;
        a_dst1[n * 8 + (t >> 1)] = pd;
    }
}

// per-dst softmax+aggregate+bias+ELU -> h[n,64]; fused layer-2 scores a_src2/a_dst2
__global__ __launch_bounds__(64) void k_gat1(
        const int* __restrict__ rowptr, const int* __restrict__ csr_src,
        const float* __restrict__ xl1, const float* __restrict__ a_src1,
        const float* __restrict__ a_dst1, const float* __restrict__ b1,
        const float* __restrict__ wsrc, const float* __restrict__ wdst,
        float* __restrict__ hout, float* __restrict__ a_src2, float* __restrict__ a_dst2) {
    int d = blockIdx.x, l = threadIdx.x;
    int hd = l >> 3;
    float adst = a_dst1[d * 8 + hd];
    int rs = rowptr[d], re = rowptr[d + 1];
    float den = 0.f, acc = 0.f;
    for (int i = rs; i < re; i++) {
        int s = csr_src[i];
        float e = a_src1[s * 8 + hd] + adst;
        e = (e > 0.f) ? e : 0.2f * e;
        float w = __expf(e);
        den += w;
        acc += w * xl1[s * 64 + l];
    }
    float o = acc / den + b1[l];
    o = (o > 0.f) ? o : (__expf(o) - 1.f);     // ELU
    hout[d * 64 + l] = o;
    // fused layer-2 attention scores: a2[d] = h[d] . (W2@att2)
    float ps = o * wsrc[l], pd = o * wdst[l];
#pragma unroll
    for (int off = 32; off; off >>= 1) {
        ps += __shfl_xor(ps, off);
        pd += __shfl_xor(pd, off);
    }
    if (l == 0) { a_src2[d] = ps; a_dst2[d] = pd; }
}

// ---------------- layer 2 ----------------

// agg[d,64] = sum_s alpha(s,d) * h[s,:]   (single head -> W2 pulled out)
__global__ __launch_bounds__(64) void k_gat2(
        const int* __restrict__ rowptr, const int* __restrict__ csr_src,
        const float* __restrict__ hbuf, const float* __restrict__ a_src2,
        const float* __restrict__ a_dst2, float* __restrict__ agg) {
    int d = blockIdx.x, l = threadIdx.x;
    float adst = a_dst2[d];
    int rs = rowptr[d], re = rowptr[d + 1];
    float den = 0.f, acc = 0.f;
    for (int i = rs; i < re; i++) {
        int s = csr_src[i];
        float e = a_src2[s] + adst;
        e = (e > 0.f) ? e : 0.2f * e;
        float w = __expf(e);
        den += w;
        acc += w * hbuf[s * 64 + l];
    }
    agg[d * 64 + l] = acc / den;
}

// out[n,256] = agg[n,64] @ W2[64,256] + b2
__global__ __launch_bounds__(256) void k_gemm_out(
        const float* __restrict__ agg, const float* __restrict__ W2,
        const float* __restrict__ b2, float* __restrict__ out) {
    int c = threadIdx.x;                 // output column 0..255
    int nb = blockIdx.x * 32;
    int cnt = NN - nb; if (cnt > 32) cnt = 32;
    float wcol[64];
#pragma unroll
    for (int k = 0; k < 64; k++) wcol[k] = W2[k * 256 + c];
    __shared__ float sa[32 * 64];
    for (int i = c; i < cnt * 64; i += 256) sa[i] = agg[nb * 64 + i];
    __syncthreads();
    float bc = b2[c];
    for (int n = 0; n < cnt; n++) {
        float acc = 0.f;
#pragma unroll
        for (int k4 = 0; k4 < 16; k4++) {
            float4 a = *(const float4*)&sa[n * 64 + k4 * 4];
            acc += a.x * wcol[k4 * 4] + a.y * wcol[k4 * 4 + 1]
                 + a.z * wcol[k4 * 4 + 2] + a.w * wcol[k4 * 4 + 3];
        }
        out[(nb + n) * 256 + c] = acc + bc;
    }
}

// ---------------- launch ----------------

extern "C" void kernel_launch(void* const* d_in, const int* in_sizes, int n_in,
                              void* d_out, int out_size, void* d_ws, size_t ws_size,
                              hipStream_t stream) {
    const float* x   = (const float*)d_in[0];
    const int*   ei  = (const int*)d_in[1];
    const float* W1  = (const float*)d_in[2];
    const float* as1 = (const float*)d_in[3];
    const float* ad1 = (const float*)d_in[4];
    const float* b1  = (const float*)d_in[5];
    const float* W2  = (const float*)d_in[6];
    const float* as2 = (const float*)d_in[7];
    const float* ad2 = (const float*)d_in[8];
    const float* b2  = (const float*)d_in[9];
    float* out = (float*)d_out;

    char* p = (char*)d_ws;
    auto alloc = [&](size_t bytes) {
        void* r = (void*)p;
        p += (bytes + 255) & ~size_t(255);
        return r;
    };
    int*   deg     = (int*)alloc(NN * 4);
    int*   rowptr  = (int*)alloc((NN + 1) * 4);
    int*   cursor  = (int*)alloc(NN * 4);
    int*   csr_src = (int*)alloc((size_t)ET * 4);
    float* xl1     = (float*)alloc((size_t)NN * 64 * 4);
    float* asrc1   = (float*)alloc((size_t)NN * 8 * 4);
    float* adst1   = (float*)alloc((size_t)NN * 8 * 4);
    float* hbuf    = (float*)alloc((size_t)NN * 64 * 4);
    float* aggbuf  = (float*)alloc((size_t)NN * 64 * 4);
    float* asrc2   = (float*)alloc(NN * 4);
    float* adst2   = (float*)alloc(NN * 4);
    float* wsrc    = (float*)alloc(64 * 4);
    float* wdst    = (float*)alloc(64 * 4);

    // CSR build
    k_zero<<<(NN + 255) / 256, 256, 0, stream>>>(deg);
    k_count<<<(ET + 255) / 256, 256, 0, stream>>>(ei, deg);
    k_scan<<<1, 1024, 0, stream>>>(deg, rowptr, cursor);
    k_scatter<<<(ET + 255) / 256, 256, 0, stream>>>(ei, cursor, csr_src);

    // precompute W2 @ att2 (independent of graph work)
    k_watt<<<1, 128, 0, stream>>>(W2, as2, ad2, wsrc, wdst);

    // layer 1
    k_gemm1<<<NN * 16 / 256, 256, 0, stream>>>(x, W1, as1, ad1, xl1, asrc1, adst1);
    k_gat1<<<NN, 64, 0, stream>>>(rowptr, csr_src, xl1, asrc1, adst1, b1,
                                  wsrc, wdst, hbuf, asrc2, adst2);

    // layer 2
    k_gat2<<<NN, 64, 0, stream>>>(rowptr, csr_src, hbuf, asrc2, adst2, aggbuf);
    k_gemm_out<<<(NN + 31) / 32, 256, 0, stream>>>(aggbuf, W2, b2, out);
}

// Round 3
// 199.549 us; speedup vs baseline: 1.5449x; 1.1698x over previous
//
#include <hip/hip_runtime.h>
#include <hip/hip_bf16.h>

#define NN 10000
#define EE 320000
#define ET (EE + NN)   // edges + self loops
#define FIN 256

// ---------------- CSR build ----------------

__global__ void k_count(const int* __restrict__ ei, int* __restrict__ deg) {
    int e = blockIdx.x * blockDim.x + threadIdx.x;
    if (e >= ET) return;
    int d = (e < EE) ? ei[EE + e] : (e - EE);
    atomicAdd(&deg[d], 1);
}

// scan (rowptr/cursor) + watt (W2 @ att2) folded into one 1024-thread block
__global__ void k_scan_watt(const int* __restrict__ deg, int* __restrict__ rowptr,
                            int* __restrict__ cursor,
                            const float* __restrict__ W2, const float* __restrict__ as2,
                            const float* __restrict__ ad2, float* __restrict__ wsrc,
                            float* __restrict__ wdst) {
    __shared__ int sums[1024];
    int tid = threadIdx.x;
    const int per = (NN + 1023) >> 10;          // 10
    int start = tid * per;
    int end   = start + per; if (end > NN) end = NN;
    int local = 0;
    if (start < NN)
        for (int i = start; i < end; i++) local += deg[i];
    sums[tid] = local;
    __syncthreads();
    for (int off = 1; off < 1024; off <<= 1) {
        int v = (tid >= off) ? sums[tid - off] : 0;
        __syncthreads();
        sums[tid] += v;
        __syncthreads();
    }
    int run = sums[tid] - local;                // exclusive prefix
    if (start < NN)
        for (int i = start; i < end; i++) { rowptr[i] = run; cursor[i] = run; run += deg[i]; }
    if (tid == 1023) rowptr[NN] = run;          // total = ET

    // independent tiny GEMV: wsrc/wdst = W2 @ att2
    if (tid < 128) {
        int k = tid & 63;
        const float* av = (tid < 64) ? as2 : ad2;
        float acc = 0.f;
#pragma unroll
        for (int c4 = 0; c4 < 64; c4++) {
            float4 w = *(const float4*)&W2[k * 256 + c4 * 4];
            float4 a = *(const float4*)&av[c4 * 4];
            acc += w.x * a.x + w.y * a.y + w.z * a.z + w.w * a.w;
        }
        if (tid < 64) wsrc[k] = acc; else wdst[k] = acc;
    }
}

__global__ void k_scatter(const int* __restrict__ ei, int* __restrict__ cursor,
                          int* __restrict__ csr_src) {
    int e = blockIdx.x * blockDim.x + threadIdx.x;
    if (e >= ET) return;
    int s, d;
    if (e < EE) { s = ei[e]; d = ei[EE + e]; }
    else        { s = e - EE; d = s; }
    int pos = atomicAdd(&cursor[d], 1);
    csr_src[pos] = s;
}

// ---------------- layer 1: LDS-tiled GEMM + fused attention scores ----------------
// xl1[n,64] = x[n,256] @ W1[256,64]; BM=64, BN=64, BK=32; 4x4 micro-tile/thread.

__global__ __launch_bounds__(256) void k_gemm1(
        const float* __restrict__ x, const float* __restrict__ W1,
        const float* __restrict__ as1, const float* __restrict__ ad1,
        float* __restrict__ xl1, float* __restrict__ a_src1, float* __restrict__ a_dst1) {
    __shared__ float xst[32][68];   // [k][row], padded: stride 272B (16B-aligned)
    __shared__ float ws[32][64];    // [k][col]
    int tid = threadIdx.x;
    int nb = blockIdx.x * 64;
    int r0 = (tid >> 4) * 4;        // rows r0..r0+3
    int c0 = (tid & 15) * 4;        // cols c0..c0+3

    float4 acc[4];
#pragma unroll
    for (int i = 0; i < 4; i++) acc[i] = make_float4(0.f, 0.f, 0.f, 0.f);

    int srow = tid >> 3;            // 0..31 (staging row, +32 second pass)
    int skf  = (tid & 7) * 4;       // k-offset within tile

    for (int kt = 0; kt < 8; kt++) {
#pragma unroll
        for (int h = 0; h < 2; h++) {
            int row = srow + h * 32;
            int rg = nb + row; if (rg > NN - 1) rg = NN - 1;
            float4 xv = *(const float4*)&x[rg * FIN + kt * 32 + skf];
            xst[skf + 0][row] = xv.x;
            xst[skf + 1][row] = xv.y;
            xst[skf + 2][row] = xv.z;
            xst[skf + 3][row] = xv.w;
        }
        int wk = tid >> 4;          // 0..15 (+16)
#pragma unroll
        for (int h = 0; h < 2; h++) {
            int k = wk + h * 16;
            *(float4*)&ws[k][c0] = *(const float4*)&W1[(kt * 32 + k) * 64 + c0];
        }
        __syncthreads();
#pragma unroll
        for (int k = 0; k < 32; k++) {
            float4 a = *(const float4*)&xst[k][r0];
            float4 b = *(const float4*)&ws[k][c0];
            acc[0].x += a.x * b.x; acc[0].y += a.x * b.y; acc[0].z += a.x * b.z; acc[0].w += a.x * b.w;
            acc[1].x += a.y * b.x; acc[1].y += a.y * b.y; acc[1].z += a.y * b.z; acc[1].w += a.y * b.w;
            acc[2].x += a.z * b.x; acc[2].y += a.z * b.y; acc[2].z += a.z * b.z; acc[2].w += a.z * b.w;
            acc[3].x += a.w * b.x; acc[3].y += a.w * b.y; acc[3].z += a.w * b.z; acc[3].w += a.w * b.w;
        }
        __syncthreads();
    }

    float4 asv = *(const float4*)&as1[c0];
    float4 adv = *(const float4*)&ad1[c0];
#pragma unroll
    for (int i = 0; i < 4; i++) {
        int n = nb + r0 + i;
        bool ok = (n < NN);
        if (ok) *(float4*)&xl1[n * 64 + c0] = acc[i];
        float ps = acc[i].x * asv.x + acc[i].y * asv.y + acc[i].z * asv.z + acc[i].w * asv.w;
        float pd = acc[i].x * adv.x + acc[i].y * adv.y + acc[i].z * adv.z + acc[i].w * adv.w;
        ps += __shfl_xor(ps, 1);
        pd += __shfl_xor(pd, 1);
        if (ok && (tid & 1) == 0) {
            a_src1[n * 8 + (c0 >> 3)] = ps;
            a_dst1[n * 8 + (c0 >> 3)] = pd;
        }
    }
}

// ---------------- GAT aggregation: 4 dsts/block, 4 edges/wave-iter ----------------

__global__ __launch_bounds__(256) void k_gat1(
        const int* __restrict__ rowptr, const int* __restrict__ csr_src,
        const float* __restrict__ xl1, const float* __restrict__ a_src1,
        const float* __restrict__ a_dst1, const float* __restrict__ b1,
        const float* __restrict__ wsrc, const float* __restrict__ wdst,
        float* __restrict__ hout, float* __restrict__ a_src2, float* __restrict__ a_dst2) {
    int d = blockIdx.x * 4 + (threadIdx.x >> 6);
    int l = threadIdx.x & 63;
    int eg = l >> 4, c4 = l & 15, c0 = c4 * 4, hd = c4 >> 1;
    float adst = a_dst1[d * 8 + hd];
    int rs = rowptr[d], re = rowptr[d + 1];
    float den = 0.f;
    float4 acc = make_float4(0.f, 0.f, 0.f, 0.f);
    for (int i = rs + eg; i < re; i += 4) {
        int s = csr_src[i];
        float e = a_src1[s * 8 + hd] + adst;
        e = (e > 0.f) ? e : 0.2f * e;
        float w = __expf(e);
        den += w;
        float4 xv = *(const float4*)&xl1[s * 64 + c0];
        acc.x += w * xv.x; acc.y += w * xv.y; acc.z += w * xv.z; acc.w += w * xv.w;
    }
    // reduce over the 4 edge-subgroups
    den += __shfl_xor(den, 16); den += __shfl_xor(den, 32);
    acc.x += __shfl_xor(acc.x, 16); acc.x += __shfl_xor(acc.x, 32);
    acc.y += __shfl_xor(acc.y, 16); acc.y += __shfl_xor(acc.y, 32);
    acc.z += __shfl_xor(acc.z, 16); acc.z += __shfl_xor(acc.z, 32);
    acc.w += __shfl_xor(acc.w, 16); acc.w += __shfl_xor(acc.w, 32);
    float inv = 1.f / den;
    float4 bv = *(const float4*)&b1[c0];
    float4 o;
    o.x = acc.x * inv + bv.x; o.y = acc.y * inv + bv.y;
    o.z = acc.z * inv + bv.z; o.w = acc.w * inv + bv.w;
    o.x = (o.x > 0.f) ? o.x : (__expf(o.x) - 1.f);
    o.y = (o.y > 0.f) ? o.y : (__expf(o.y) - 1.f);
    o.z = (o.z > 0.f) ? o.z : (__expf(o.z) - 1.f);
    o.w = (o.w > 0.f) ? o.w : (__expf(o.w) - 1.f);
    if (eg == 0) *(float4*)&hout[d * 64 + c0] = o;
    // fused layer-2 scores: a2[d] = h[d] . (W2@att2)
    float4 wsv = *(const float4*)&wsrc[c0];
    float4 wdv = *(const float4*)&wdst[c0];
    float ps = o.x * wsv.x + o.y * wsv.y + o.z * wsv.z + o.w * wsv.w;
    float pd = o.x * wdv.x + o.y * wdv.y + o.z * wdv.z + o.w * wdv.w;
#pragma unroll
    for (int off = 8; off; off >>= 1) {
        ps += __shfl_xor(ps, off);
        pd += __shfl_xor(pd, off);
    }
    if (l == 0) { a_src2[d] = ps; a_dst2[d] = pd; }
}

__global__ __launch_bounds__(256) void k_gat2(
        const int* __restrict__ rowptr, const int* __restrict__ csr_src,
        const float* __restrict__ hbuf, const float* __restrict__ a_src2,
        const float* __restrict__ a_dst2, float* __restrict__ agg) {
    int d = blockIdx.x * 4 + (threadIdx.x >> 6);
    int l = threadIdx.x & 63;
    int eg = l >> 4, c0 = (l & 15) * 4;
    float adst = a_dst2[d];
    int rs = rowptr[d], re = rowptr[d + 1];
    float den = 0.f;
    float4 acc = make_float4(0.f, 0.f, 0.f, 0.f);
    for (int i = rs + eg; i < re; i += 4) {
        int s = csr_src[i];
        float e = a_src2[s] + adst;
        e = (e > 0.f) ? e : 0.2f * e;
        float w = __expf(e);
        den += w;
        float4 hv = *(const float4*)&hbuf[s * 64 + c0];
        acc.x += w * hv.x; acc.y += w * hv.y; acc.z += w * hv.z; acc.w += w * hv.w;
    }
    den += __shfl_xor(den, 16); den += __shfl_xor(den, 32);
    acc.x += __shfl_xor(acc.x, 16); acc.x += __shfl_xor(acc.x, 32);
    acc.y += __shfl_xor(acc.y, 16); acc.y += __shfl_xor(acc.y, 32);
    acc.z += __shfl_xor(acc.z, 16); acc.z += __shfl_xor(acc.z, 32);
    acc.w += __shfl_xor(acc.w, 16); acc.w += __shfl_xor(acc.w, 32);
    if (eg == 0) {
        float inv = 1.f / den;
        *(float4*)&agg[d * 64 + c0] =
            make_float4(acc.x * inv, acc.y * inv, acc.z * inv, acc.w * inv);
    }
}

// out[n,256] = agg[n,64] @ W2[64,256] + b2
__global__ __launch_bounds__(256) void k_gemm_out(
        const float* __restrict__ agg, const float* __restrict__ W2,
        const float* __restrict__ b2, float* __restrict__ out) {
    int c = threadIdx.x;                 // output column 0..255
    int nb = blockIdx.x * 32;
    int cnt = NN - nb; if (cnt > 32) cnt = 32;
    float wcol[64];
#pragma unroll
    for (int k = 0; k < 64; k++) wcol[k] = W2[k * 256 + c];
    __shared__ float sa[32 * 64];
    for (int i = c; i < cnt * 64; i += 256) sa[i] = agg[nb * 64 + i];
    __syncthreads();
    float bc = b2[c];
    for (int n = 0; n < cnt; n++) {
        float acc = 0.f;
#pragma unroll
        for (int k4 = 0; k4 < 16; k4++) {
            float4 a = *(const float4*)&sa[n * 64 + k4 * 4];
            acc += a.x * wcol[k4 * 4] + a.y * wcol[k4 * 4 + 1]
                 + a.z * wcol[k4 * 4 + 2] + a.w * wcol[k4 * 4 + 3];
        }
        out[(nb + n) * 256 + c] = acc + bc;
    }
}

// ---------------- launch ----------------

extern "C" void kernel_launch(void* const* d_in, const int* in_sizes, int n_in,
                              void* d_out, int out_size, void* d_ws, size_t ws_size,
                              hipStream_t stream) {
    const float* x   = (const float*)d_in[0];
    const int*   ei  = (const int*)d_in[1];
    const float* W1  = (const float*)d_in[2];
    const float* as1 = (const float*)d_in[3];
    const float* ad1 = (const float*)d_in[4];
    const float* b1  = (const float*)d_in[5];
    const float* W2  = (const float*)d_in[6];
    const float* as2 = (const float*)d_in[7];
    const float* ad2 = (const float*)d_in[8];
    const float* b2  = (const float*)d_in[9];
    float* out = (float*)d_out;

    char* p = (char*)d_ws;
    auto alloc = [&](size_t bytes) {
        void* r = (void*)p;
        p += (bytes + 255) & ~size_t(255);
        return r;
    };
    int*   deg     = (int*)alloc(NN * 4);
    int*   rowptr  = (int*)alloc((NN + 1) * 4);
    int*   cursor  = (int*)alloc(NN * 4);
    int*   csr_src = (int*)alloc((size_t)ET * 4);
    float* xl1     = (float*)alloc((size_t)NN * 64 * 4);
    float* asrc1   = (float*)alloc((size_t)NN * 8 * 4);
    float* adst1   = (float*)alloc((size_t)NN * 8 * 4);
    float* hbuf    = (float*)alloc((size_t)NN * 64 * 4);
    float* aggbuf  = (float*)alloc((size_t)NN * 64 * 4);
    float* asrc2   = (float*)alloc(NN * 4);
    float* adst2   = (float*)alloc(NN * 4);
    float* wsrc    = (float*)alloc(64 * 4);
    float* wdst    = (float*)alloc(64 * 4);

    // CSR build
    hipMemsetAsync(deg, 0, NN * 4, stream);
    k_count<<<(ET + 255) / 256, 256, 0, stream>>>(ei, deg);
    k_scan_watt<<<1, 1024, 0, stream>>>(deg, rowptr, cursor, W2, as2, ad2, wsrc, wdst);
    k_scatter<<<(ET + 255) / 256, 256, 0, stream>>>(ei, cursor, csr_src);

    // layer 1
    k_gemm1<<<(NN + 63) / 64, 256, 0, stream>>>(x, W1, as1, ad1, xl1, asrc1, adst1);
    k_gat1<<<NN / 4, 256, 0, stream>>>(rowptr, csr_src, xl1, asrc1, adst1, b1,
                                       wsrc, wdst, hbuf, asrc2, adst2);

    // layer 2
    k_gat2<<<NN / 4, 256, 0, stream>>>(rowptr, csr_src, hbuf, asrc2, adst2, aggbuf);
    k_gemm_out<<<(NN + 31) / 32, 256, 0, stream>>>(aggbuf, W2, b2, out);
}

// Round 6
// 179.724 us; speedup vs baseline: 1.7154x; 1.1103x over previous
//
#include <hip/hip_runtime.h>
#include <hip/hip_bf16.h>

#define NN 10000
#define EE 320000
#define ET (EE + NN)   // edges + self loops
#define FIN 256
#define GEMM1_BLOCKS ((NN + 63) / 64)          // 157
#define COUNT_BLOCKS ((ET + 255) / 256)        // 1290

// ---------------- fused: layer-1 GEMM (+att scores) and degree count ----------------
// Blocks [0, GEMM1_BLOCKS): LDS-tiled xl1 = x @ W1, fused a_src1/a_dst1 epilogue.
// Blocks [GEMM1_BLOCKS, +COUNT_BLOCKS): atomic degree count (independent work).

__global__ __launch_bounds__(256) void k_gemm1_count(
        const float* __restrict__ x, const float* __restrict__ W1,
        const float* __restrict__ as1, const float* __restrict__ ad1,
        const int* __restrict__ ei, int* __restrict__ deg,
        float* __restrict__ xl1, float* __restrict__ a_src1, float* __restrict__ a_dst1) {
    if (blockIdx.x >= GEMM1_BLOCKS) {
        int e = (blockIdx.x - GEMM1_BLOCKS) * 256 + threadIdx.x;
        if (e < ET) {
            int d = (e < EE) ? ei[EE + e] : (e - EE);
            atomicAdd(&deg[d], 1);
        }
        return;
    }
    __shared__ float xst[32][68];   // [k][row], padded
    __shared__ float ws[32][64];    // [k][col]
    int tid = threadIdx.x;
    int nb = blockIdx.x * 64;
    int r0 = (tid >> 4) * 4;
    int c0 = (tid & 15) * 4;

    float4 acc[4];
#pragma unroll
    for (int i = 0; i < 4; i++) acc[i] = make_float4(0.f, 0.f, 0.f, 0.f);

    int srow = tid >> 3;
    int skf  = (tid & 7) * 4;

    for (int kt = 0; kt < 8; kt++) {
#pragma unroll
        for (int h = 0; h < 2; h++) {
            int row = srow + h * 32;
            int rg = nb + row; if (rg > NN - 1) rg = NN - 1;
            float4 xv = *(const float4*)&x[rg * FIN + kt * 32 + skf];
            xst[skf + 0][row] = xv.x;
            xst[skf + 1][row] = xv.y;
            xst[skf + 2][row] = xv.z;
            xst[skf + 3][row] = xv.w;
        }
        int wk = tid >> 4;
#pragma unroll
        for (int h = 0; h < 2; h++) {
            int k = wk + h * 16;
            *(float4*)&ws[k][c0] = *(const float4*)&W1[(kt * 32 + k) * 64 + c0];
        }
        __syncthreads();
#pragma unroll
        for (int k = 0; k < 32; k++) {
            float4 a = *(const float4*)&xst[k][r0];
            float4 b = *(const float4*)&ws[k][c0];
            acc[0].x += a.x * b.x; acc[0].y += a.x * b.y; acc[0].z += a.x * b.z; acc[0].w += a.x * b.w;
            acc[1].x += a.y * b.x; acc[1].y += a.y * b.y; acc[1].z += a.y * b.z; acc[1].w += a.y * b.w;
            acc[2].x += a.z * b.x; acc[2].y += a.z * b.y; acc[2].z += a.z * b.z; acc[2].w += a.z * b.w;
            acc[3].x += a.w * b.x; acc[3].y += a.w * b.y; acc[3].z += a.w * b.z; acc[3].w += a.w * b.w;
        }
        __syncthreads();
    }

    float4 asv = *(const float4*)&as1[c0];
    float4 adv = *(const float4*)&ad1[c0];
#pragma unroll
    for (int i = 0; i < 4; i++) {
        int n = nb + r0 + i;
        bool ok = (n < NN);
        if (ok) *(float4*)&xl1[n * 64 + c0] = acc[i];
        float ps = acc[i].x * asv.x + acc[i].y * asv.y + acc[i].z * asv.z + acc[i].w * asv.w;
        float pd = acc[i].x * adv.x + acc[i].y * adv.y + acc[i].z * adv.z + acc[i].w * adv.w;
        ps += __shfl_xor(ps, 1);
        pd += __shfl_xor(pd, 1);
        if (ok && (tid & 1) == 0) {
            a_src1[n * 8 + (c0 >> 3)] = ps;
            a_dst1[n * 8 + (c0 >> 3)] = pd;
        }
    }
}

// ---------------- scan (rowptr/cursor) + watt (W2 @ att2), single block ----------------

__global__ void k_scan_watt(const int* __restrict__ deg, int* __restrict__ rowptr,
                            int* __restrict__ cursor,
                            const float* __restrict__ W2, const float* __restrict__ as2,
                            const float* __restrict__ ad2, float* __restrict__ wsrc,
                            float* __restrict__ wdst) {
    __shared__ int sums[1024];
    int tid = threadIdx.x;
    const int per = (NN + 1023) >> 10;          // 10
    int start = tid * per;
    int end   = start + per; if (end > NN) end = NN;
    int local = 0;
    if (start < NN)
        for (int i = start; i < end; i++) local += deg[i];
    sums[tid] = local;
    __syncthreads();
    for (int off = 1; off < 1024; off <<= 1) {
        int v = (tid >= off) ? sums[tid - off] : 0;
        __syncthreads();
        sums[tid] += v;
        __syncthreads();
    }
    int run = sums[tid] - local;                // exclusive prefix
    if (start < NN)
        for (int i = start; i < end; i++) { rowptr[i] = run; cursor[i] = run; run += deg[i]; }
    if (tid == 1023) rowptr[NN] = run;          // total = ET

    if (tid < 128) {
        int k = tid & 63;
        const float* av = (tid < 64) ? as2 : ad2;
        float acc = 0.f;
#pragma unroll
        for (int c4 = 0; c4 < 64; c4++) {
            float4 w = *(const float4*)&W2[k * 256 + c4 * 4];
            float4 a = *(const float4*)&av[c4 * 4];
            acc += w.x * a.x + w.y * a.y + w.z * a.z + w.w * a.w;
        }
        if (tid < 64) wsrc[k] = acc; else wdst[k] = acc;
    }
}

__global__ void k_scatter(const int* __restrict__ ei, int* __restrict__ cursor,
                          int* __restrict__ csr_src) {
    int e = blockIdx.x * blockDim.x + threadIdx.x;
    if (e >= ET) return;
    int s, d;
    if (e < EE) { s = ei[e]; d = ei[EE + e]; }
    else        { s = e - EE; d = s; }
    int pos = atomicAdd(&cursor[d], 1);
    csr_src[pos] = s;
}

// ---------------- GAT layer 1: 4 dsts/block, 2x-pipelined edge loop ----------------

__global__ __launch_bounds__(256) void k_gat1(
        const int* __restrict__ rowptr, const int* __restrict__ csr_src,
        const float* __restrict__ xl1, const float* __restrict__ a_src1,
        const float* __restrict__ a_dst1, const float* __restrict__ b1,
        const float* __restrict__ wsrc, const float* __restrict__ wdst,
        float* __restrict__ hout, float* __restrict__ a_src2, float* __restrict__ a_dst2) {
    int d = blockIdx.x * 4 + (threadIdx.x >> 6);
    int l = threadIdx.x & 63;
    int eg = l >> 4, c4 = l & 15, c0 = c4 * 4, hd = c4 >> 1;
    float adst = a_dst1[d * 8 + hd];
    int rs = rowptr[d], re = rowptr[d + 1];
    float den = 0.f;
    float4 acc = make_float4(0.f, 0.f, 0.f, 0.f);
    int i = rs + eg;
    for (; i + 4 < re; i += 8) {           // two edges per subgroup-iter (MLP x2)
        int s0 = csr_src[i];
        int s1 = csr_src[i + 4];
        float a0 = a_src1[s0 * 8 + hd];
        float a1 = a_src1[s1 * 8 + hd];
        float4 x0 = *(const float4*)&xl1[s0 * 64 + c0];
        float4 x1 = *(const float4*)&xl1[s1 * 64 + c0];
        float e0 = a0 + adst; e0 = (e0 > 0.f) ? e0 : 0.2f * e0;
        float e1 = a1 + adst; e1 = (e1 > 0.f) ? e1 : 0.2f * e1;
        float w0 = __expf(e0), w1 = __expf(e1);
        den += w0 + w1;
        acc.x += w0 * x0.x + w1 * x1.x;
        acc.y += w0 * x0.y + w1 * x1.y;
        acc.z += w0 * x0.z + w1 * x1.z;
        acc.w += w0 * x0.w + w1 * x1.w;
    }
    if (i < re) {
        int s = csr_src[i];
        float e = a_src1[s * 8 + hd] + adst;
        e = (e > 0.f) ? e : 0.2f * e;
        float w = __expf(e);
        den += w;
        float4 xv = *(const float4*)&xl1[s * 64 + c0];
        acc.x += w * xv.x; acc.y += w * xv.y; acc.z += w * xv.z; acc.w += w * xv.w;
    }
    den += __shfl_xor(den, 16); den += __shfl_xor(den, 32);
    acc.x += __shfl_xor(acc.x, 16); acc.x += __shfl_xor(acc.x, 32);
    acc.y += __shfl_xor(acc.y, 16); acc.y += __shfl_xor(acc.y, 32);
    acc.z += __shfl_xor(acc.z, 16); acc.z += __shfl_xor(acc.z, 32);
    acc.w += __shfl_xor(acc.w, 16); acc.w += __shfl_xor(acc.w, 32);
    float inv = 1.f / den;
    float4 bv = *(const float4*)&b1[c0];
    float4 o;
    o.x = acc.x * inv + bv.x; o.y = acc.y * inv + bv.y;
    o.z = acc.z * inv + bv.z; o.w = acc.w * inv + bv.w;
    o.x = (o.x > 0.f) ? o.x : (__expf(o.x) - 1.f);
    o.y = (o.y > 0.f) ? o.y : (__expf(o.y) - 1.f);
    o.z = (o.z > 0.f) ? o.z : (__expf(o.z) - 1.f);
    o.w = (o.w > 0.f) ? o.w : (__expf(o.w) - 1.f);
    if (eg == 0) *(float4*)&hout[d * 64 + c0] = o;
    // fused layer-2 scores: a2[d] = h[d] . (W2@att2)
    float4 wsv = *(const float4*)&wsrc[c0];
    float4 wdv = *(const float4*)&wdst[c0];
    float ps = o.x * wsv.x + o.y * wsv.y + o.z * wsv.z + o.w * wsv.w;
    float pd = o.x * wdv.x + o.y * wdv.y + o.z * wdv.z + o.w * wdv.w;
#pragma unroll
    for (int off = 8; off; off >>= 1) {
        ps += __shfl_xor(ps, off);
        pd += __shfl_xor(pd, off);
    }
    if (l == 0) { a_src2[d] = ps; a_dst2[d] = pd; }
}

// ---------------- GAT layer 2 + output GEMM fused ----------------
// Aggregate 4 dsts (one per wave), stage agg rows in LDS, then 64x256 matvec:
// out[d,:] = agg[d,:] @ W2 + b2.

__global__ __launch_bounds__(256) void k_gat2_out(
        const int* __restrict__ rowptr, const int* __restrict__ csr_src,
        const float* __restrict__ hbuf, const float* __restrict__ a_src2,
        const float* __restrict__ a_dst2, const float* __restrict__ W2,
        const float* __restrict__ b2, float* __restrict__ out) {
    __shared__ float sagg[4][64];
    int wid = threadIdx.x >> 6;
    int d = blockIdx.x * 4 + wid;
    int l = threadIdx.x & 63;
    int eg = l >> 4, c0 = (l & 15) * 4;
    float adst = a_dst2[d];
    int rs = rowptr[d], re = rowptr[d + 1];
    float den = 0.f;
    float4 acc = make_float4(0.f, 0.f, 0.f, 0.f);
    int i = rs + eg;
    for (; i + 4 < re; i += 8) {
        int s0 = csr_src[i];
        int s1 = csr_src[i + 4];
        float a0 = a_src2[s0];
        float a1 = a_src2[s1];
        float4 h0 = *(const float4*)&hbuf[s0 * 64 + c0];
        float4 h1 = *(const float4*)&hbuf[s1 * 64 + c0];
        float e0 = a0 + adst; e0 = (e0 > 0.f) ? e0 : 0.2f * e0;
        float e1 = a1 + adst; e1 = (e1 > 0.f) ? e1 : 0.2f * e1;
        float w0 = __expf(e0), w1 = __expf(e1);
        den += w0 + w1;
        acc.x += w0 * h0.x + w1 * h1.x;
        acc.y += w0 * h0.y + w1 * h1.y;
        acc.z += w0 * h0.z + w1 * h1.z;
        acc.w += w0 * h0.w + w1 * h1.w;
    }
    if (i < re) {
        int s = csr_src[i];
        float e = a_src2[s] + adst;
        e = (e > 0.f) ? e : 0.2f * e;
        float w = __expf(e);
        den += w;
        float4 hv = *(const float4*)&hbuf[s * 64 + c0];
        acc.x += w * hv.x; acc.y += w * hv.y; acc.z += w * hv.z; acc.w += w * hv.w;
    }
    den += __shfl_xor(den, 16); den += __shfl_xor(den, 32);
    acc.x += __shfl_xor(acc.x, 16); acc.x += __shfl_xor(acc.x, 32);
    acc.y += __shfl_xor(acc.y, 16); acc.y += __shfl_xor(acc.y, 32);
    acc.z += __shfl_xor(acc.z, 16); acc.z += __shfl_xor(acc.z, 32);
    acc.w += __shfl_xor(acc.w, 16); acc.w += __shfl_xor(acc.w, 32);
    if (eg == 0) {
        float inv = 1.f / den;
        *(float4*)&sagg[wid][c0] =
            make_float4(acc.x * inv, acc.y * inv, acc.z * inv, acc.w * inv);
    }
    __syncthreads();
    // matvec: thread c computes column c for all 4 dsts of this block
    int c = threadIdx.x;
    float o0 = 0.f, o1 = 0.f, o2 = 0.f, o3 = 0.f;
#pragma unroll 8
    for (int k = 0; k < 64; k++) {
        float w = W2[k * 256 + c];          // coalesced, L2-hit
        o0 += sagg[0][k] * w;               // LDS broadcasts
        o1 += sagg[1][k] * w;
        o2 += sagg[2][k] * w;
        o3 += sagg[3][k] * w;
    }
    float bc = b2[c];
    int nb = blockIdx.x * 4;
    out[(nb + 0) * 256 + c] = o0 + bc;
    out[(nb + 1) * 256 + c] = o1 + bc;
    out[(nb + 2) * 256 + c] = o2 + bc;
    out[(nb + 3) * 256 + c] = o3 + bc;
}

// ---------------- launch ----------------

extern "C" void kernel_launch(void* const* d_in, const int* in_sizes, int n_in,
                              void* d_out, int out_size, void* d_ws, size_t ws_size,
                              hipStream_t stream) {
    const float* x   = (const float*)d_in[0];
    const int*   ei  = (const int*)d_in[1];
    const float* W1  = (const float*)d_in[2];
    const float* as1 = (const float*)d_in[3];
    const float* ad1 = (const float*)d_in[4];
    const float* b1  = (const float*)d_in[5];
    const float* W2  = (const float*)d_in[6];
    const float* as2 = (const float*)d_in[7];
    const float* ad2 = (const float*)d_in[8];
    const float* b2  = (const float*)d_in[9];
    float* out = (float*)d_out;

    char* p = (char*)d_ws;
    auto alloc = [&](size_t bytes) {
        void* r = (void*)p;
        p += (bytes + 255) & ~size_t(255);
        return r;
    };
    int*   deg     = (int*)alloc(NN * 4);
    int*   rowptr  = (int*)alloc((NN + 1) * 4);
    int*   cursor  = (int*)alloc(NN * 4);
    int*   csr_src = (int*)alloc((size_t)ET * 4);
    float* xl1     = (float*)alloc((size_t)NN * 64 * 4);
    float* asrc1   = (float*)alloc((size_t)NN * 8 * 4);
    float* adst1   = (float*)alloc((size_t)NN * 8 * 4);
    float* hbuf    = (float*)alloc((size_t)NN * 64 * 4);
    float* asrc2   = (float*)alloc(NN * 4);
    float* adst2   = (float*)alloc(NN * 4);
    float* wsrc    = (float*)alloc(64 * 4);
    float* wdst    = (float*)alloc(64 * 4);

    hipMemsetAsync(deg, 0, NN * 4, stream);

    // layer-1 GEMM + degree count (independent, one dispatch)
    k_gemm1_count<<<GEMM1_BLOCKS + COUNT_BLOCKS, 256, 0, stream>>>(
        x, W1, as1, ad1, ei, deg, xl1, asrc1, adst1);

    k_scan_watt<<<1, 1024, 0, stream>>>(deg, rowptr, cursor, W2, as2, ad2, wsrc, wdst);
    k_scatter<<<COUNT_BLOCKS, 256, 0, stream>>>(ei, cursor, csr_src);

    k_gat1<<<NN / 4, 256, 0, stream>>>(rowptr, csr_src, xl1, asrc1, adst1, b1,
                                       wsrc, wdst, hbuf, asrc2, adst2);
    k_gat2_out<<<NN / 4, 256, 0, stream>>>(rowptr, csr_src, hbuf, asrc2, adst2,
                                           W2, b2, out);
}